// Round 12
// baseline (189.177 us; speedup 1.0000x reference)
//
#include <hip/hip_runtime.h>
#include <hip/hip_bf16.h>

// B=2, S=2048, E=1024, H=16, HD=KD=VD=64. fp32 I/O, bf16 MFMA internals.
// R21: attn is ISSUE-PORT bound (VALU 58% + MFMA 25% = 83%; ~290cyc/step-slot
// matches the per-step instruction count x 2 waves). Largest removable block:
// 16 shl/and per half-step unpacking bf16 masks from u32. Fix: store mask
// pre-scaled as F32 in exact fragment order (maskPF, 16MB) -> exp path is
// mul/exp2/cvt only (-16 VALU, +2 loads per half-step), one mask pointer.
// attn otherwise = R18 structure. out_gemm = R20 (XCD-local). qkv unchanged.
#define SS 2048
#define EE 1024
#define SCALE 0.125f
#define LOG2E 1.44269504088896f

typedef __attribute__((ext_vector_type(8))) short short8;
typedef __attribute__((ext_vector_type(4))) float float4v;
typedef __attribute__((ext_vector_type(4))) unsigned int uint4v;

__device__ __forceinline__ unsigned short f2bf(float f) {
  unsigned int u = __float_as_uint(f);
  unsigned int lsb = (u >> 16) & 1u;
  u += 0x7fffu + lsb;           // RNE
  return (unsigned short)(u >> 16);
}
__device__ __forceinline__ unsigned int pk2bf(float a, float b) {
  __hip_bfloat162 h = __float22bfloat162_rn(float2{a, b});
  return *reinterpret_cast<unsigned int*>(&h);
}

// ---------------------------------------------------------------------------
// Kernel 1 (fused): blocks 0..511 = QKV projection GEMM (local W3T);
// 512..4607 = mask pack -> maskPF (f32, frag order, folds SCALE*log2e);
// 4608..4863 = Wo fp32 [k][n] -> WoT bf16 [n][k].
//  maskPF[((w*64+step)*64+lane)*16 + j], j = t*8 + sb*4 + hh*2 + p
//    = c * mask[(w*2+t)*16 + (lane&15)][step*32 + ((j&7)>>2)*16 + (lane>>4)*4
//      + (j&3)]   (w = q-tile/32 of the attn wave)
//  Kp[bh][step][frag=sb*2+part][lane=g*16+(s&15)][j] = K[s][part*32+g*8+j]
//  Vf[bh][step][nb][lane=(pos>>3)*16+(d&15)][pos&7]  = V[s][d], pos=perm(s&31)
// ---------------------------------------------------------------------------
__global__ __launch_bounds__(256) void fused_qkv(
    const float* __restrict__ x,
    const float* __restrict__ Wq, const float* __restrict__ Wk,
    const float* __restrict__ Wv,
    const float* __restrict__ bq, const float* __restrict__ bk,
    const float* __restrict__ bv,
    const float* __restrict__ mask, const float* __restrict__ Wo,
    unsigned short* __restrict__ Q, unsigned short* __restrict__ Kp,
    unsigned short* __restrict__ Vf,
    float* __restrict__ maskPF, unsigned short* __restrict__ WoT)
{
  __shared__ __align__(16) unsigned short w3t[192 * 72];
  __shared__ __align__(16) unsigned short xt[64 * 72];
  __shared__ __align__(16) unsigned short ob[12288];   // Q | Kp | Vf half-tile
  __shared__ float sBias[192];
  __shared__ unsigned short t[64 * 65];
  int blk = blockIdx.x;
  int tid = threadIdx.x;

  if (blk >= 512) {
    if (blk < 4608) {
      // ---- mask pack -> f32 fragment order ----
      int task = (blk - 512) * 256 + tid;        // 0..1048575
      int f4 = task & 3;                         // which float4 of the 16
      int lane = (task >> 2) & 63;
      int step = (task >> 8) & 63;
      int w = task >> 14;                        // wave q-tile 0..63
      int li = lane & 15, g = lane >> 4;
      int tt = f4 >> 1, half16 = f4 & 1;
      const float c = SCALE * LOG2E;
      int row = (w * 2 + tt) * 16 + li;
      int colbase = step * 32 + half16 * 16 + g * 4;
      float4 a = *(const float4*)(mask + (size_t)row * SS + colbase);
      float4v o; o[0] = a.x * c; o[1] = a.y * c; o[2] = a.z * c; o[3] = a.w * c;
      *(float4v*)(maskPF + (size_t)task * 4) = o;
      return;
    }
    // ---- Wo transpose: 64x64 tile per block ----
    int wblk = blk - 4608;                   // 0..255
    int k0 = (wblk >> 4) * 64, n0 = (wblk & 15) * 64;
#pragma unroll
    for (int i = 0; i < 16; ++i) {
      int e = tid + i * 256; int kk = e >> 6, nn = e & 63;
      t[nn * 65 + kk] = f2bf(Wo[(size_t)(k0 + kk) * 1024 + n0 + nn]);
    }
    __syncthreads();
#pragma unroll
    for (int i = 0; i < 16; ++i) {
      int e = tid + i * 256; int nn = e >> 6, kk = e & 63;
      WoT[(size_t)(n0 + nn) * 1024 + k0 + kk] = t[nn * 65 + kk];
    }
    return;
  }

  // ---- QKV projection ----
  int bh = blk >> 4;
  int s0blk = (blk & 15) * 128;
  int b = bh >> 4, h = bh & 15;
  int wv = tid >> 6, lane = tid & 63;
  int li = lane & 15, g = lane >> 4;

  // build w3t locally: w3t[(m*64+n)*72 + d] = bf16(W[d][n])  (W row-major)
  {
    const float* Ws[3] = {Wq, Wk, Wv};
#pragma unroll
    for (int m = 0; m < 3; ++m) {
      const float* W = Ws[m];
#pragma unroll
      for (int i = 0; i < 16; ++i) {
        int e = tid + i * 256; int d = e >> 6, n = e & 63;
        w3t[(m * 64 + n) * 72 + d] = f2bf(W[e]);
      }
    }
  }
  if (tid < 192) sBias[tid] = (tid < 64) ? bq[tid] : (tid < 128 ? bk[tid - 64] : bv[tid - 128]);

  for (int half = 0; half < 2; ++half) {
    int s0 = s0blk + half * 64;
    if (half) __syncthreads();        // prior half's ob/xt reads done
    const float* xbase = x + ((size_t)(b * SS + s0)) * EE + h * 64;
#pragma unroll
    for (int it = 0; it < 4; ++it) {
      int flat = tid + it * 256;
      int row = flat >> 4, ch = flat & 15;
      float4 v = *(const float4*)(xbase + (size_t)row * EE + ch * 4);
      uint2 u; u.x = pk2bf(v.x, v.y); u.y = pk2bf(v.z, v.w);
      *(uint2*)(xt + row * 72 + ch * 4) = u;
    }
    __syncthreads();   // covers w3t/sBias (half 0) and xt

    int mrow = wv * 16;
    short8 af[2];
#pragma unroll
    for (int ks = 0; ks < 2; ++ks)
      af[ks] = *(const short8*)(xt + (mrow + li) * 72 + ks * 32 + g * 8);

    float4v acc[12];
#pragma unroll
    for (int i = 0; i < 12; ++i) acc[i] = (float4v){0, 0, 0, 0};
#pragma unroll
    for (int ks = 0; ks < 2; ++ks)
#pragma unroll
      for (int nb = 0; nb < 12; ++nb) {
        short8 bfr = *(const short8*)(w3t + (nb * 16 + li) * 72 + ks * 32 + g * 8);
        acc[nb] = __builtin_amdgcn_mfma_f32_16x16x32_bf16(af[ks], bfr, acc[nb], 0, 0, 0);
      }

    // scatter into LDS reorder buffer
#pragma unroll
    for (int nb = 0; nb < 12; ++nb) {
      float bias = sBias[nb * 16 + li];
      int mtx = nb >> 2, sub = nb & 3;
#pragma unroll
      for (int r = 0; r < 4; ++r) {
        unsigned short v = f2bf(acc[nb][r] + bias);
        int sl = mrow + g * 4 + r;         // 0..63 local row
        int stp = sl >> 5, s5 = sl & 31;
        if (mtx == 0) {
          ob[sl * 64 + sub * 16 + li] = v;
        } else if (mtx == 1) {
          int sb = s5 >> 4, lik = s5 & 15;
          int part = sub >> 1;
          int gk = ((sub & 1) << 1) | (li >> 3);
          ob[4096 + stp * 2048 + (sb * 2 + part) * 512 + (gk * 16 + lik) * 8 + (li & 7)] = v;
        } else {
          int pos = ((s5 >> 2) & 3) * 8 + ((s5 >> 4) & 1) * 4 + (s5 & 3);
          ob[8192 + stp * 2048 + sub * 512 + ((pos >> 3) * 16 + li) * 8 + (pos & 7)] = v;
        }
      }
    }
    __syncthreads();

    // coalesced b128 stores: 1536 slots of 8 elems
    unsigned short* Qg = Q + ((size_t)bh * SS + s0) * 64;
    unsigned short* Kg = Kp + (size_t)bh * 131072 + (s0 >> 5) * 2048;
    unsigned short* Vg = Vf + (size_t)bh * 131072 + (s0 >> 5) * 2048;
#pragma unroll
    for (int i = 0; i < 6; ++i) {
      int slot = tid + i * 256;          // 0..1535
      int rgn = slot >> 9, off = (slot & 511) * 8;
      short8 v = *(const short8*)(ob + rgn * 4096 + off);
      unsigned short* dst = (rgn == 0) ? (Qg + off) : (rgn == 1 ? (Kg + off) : (Vg + off));
      *(short8*)dst = v;
    }
  }
}

// ---------------------------------------------------------------------------
// Kernel 2: flash attention (R18 structure; R21 = f32 fragment-order mask).
// Wave = 32 q-rows of one bh; block = 4 independent waves; grid 512
// (bijective XCD swizzle). All K/V/mask fragments loaded global->registers.
// S^T formulation; den via ones-row MFMA. 1-step software pipeline of st;
// depth-2 K/V/mask ping-pong; strength-reduced reload pointers; setprio.
// exp path: p = exp2(st * m) with m loaded as f32 -- no unpack VALU.
// ---------------------------------------------------------------------------
__global__ __launch_bounds__(256) void attn_kernel(
    const unsigned short* __restrict__ Q, const unsigned short* __restrict__ Kp,
    const unsigned short* __restrict__ Vf, const float* __restrict__ maskPF,
    unsigned short* __restrict__ AO)
{
  __shared__ __align__(16) unsigned short tr_all[4 * 32 * 72];  // epilogue only
  int tid = threadIdx.x, wv = tid >> 6, lane = tid & 63;
  int li = lane & 15, g = lane >> 4;
  // bijective XCD swizzle: 512 = 8 XCDs x 64 -> XCD x hosts bh [4x, 4x+4)
  int virt = (blockIdx.x & 7) * 64 + (blockIdx.x >> 3);
  int wave_id = virt * 4 + wv;              // 0..2047
  int bh = wave_id >> 6;
  int q0 = (wave_id & 63) * 32;

  short8 qf[2][2];
#pragma unroll
  for (int t = 0; t < 2; ++t) {
    const unsigned short* Qb = Q + ((size_t)bh * SS + q0 + t * 16 + li) * 64;
    qf[t][0] = *(const short8*)(Qb + g * 8);
    qf[t][1] = *(const short8*)(Qb + 32 + g * 8);
  }

  const unsigned short* Kg = Kp + (size_t)bh * 131072 + lane * 8;
  const unsigned short* Vg = Vf + (size_t)bh * 131072 + lane * 8;
  // f32 mask base: 16 floats per (w, step, lane); w = q0/32
  const float* Mg = maskPF + (size_t)(q0 >> 5) * 65536 + (size_t)lane * 16;

  unsigned short ov = (li == 0) ? (unsigned short)0x3F80 : (unsigned short)0;
  short8 vones = {(short)ov, (short)ov, (short)ov, (short)ov,
                  (short)ov, (short)ov, (short)ov, (short)ov};

  float4v acc[2][4];
#pragma unroll
  for (int t = 0; t < 2; ++t)
#pragma unroll
    for (int nb = 0; nb < 4; ++nb) acc[t][nb] = (float4v){0, 0, 0, 0};
  float4v accd[2] = {{0, 0, 0, 0}, {0, 0, 0, 0}};

  // carried score registers (software-pipeline stage): st[t][sb] holds the
  // QK output for the step whose exp has NOT run yet.
  float4v st[2][2];

  // ping-pong prefetch sets: A = even steps, B = odd steps (depth-2)
  short8 kA[4], kB[4], vA[4], vB[4];
  float4v mAf[4], mBf[4];     // mf[t*2+sb][hh*2+p] = mask for st[t][sb][2hh+p]
  {
    short8 k0[4];
#pragma unroll
    for (int i = 0; i < 4; ++i) {
      k0[i] = *(const short8*)(Kg + i * 512);
      kA[i] = *(const short8*)(Kg + 2048 + i * 512);
      kB[i] = *(const short8*)(Kg + 2 * 2048 + i * 512);
      vA[i] = *(const short8*)(Vg + i * 512);
      vB[i] = *(const short8*)(Vg + 2048 + i * 512);
      mAf[i] = *(const float4v*)(Mg + i * 4);
      mBf[i] = *(const float4v*)(Mg + 1024 + i * 4);
    }
    // prologue QK: st <- scores(step 0)
#pragma unroll
    for (int t = 0; t < 2; ++t)
#pragma unroll
      for (int sb = 0; sb < 2; ++sb) {
        float4v s = {0, 0, 0, 0};
        s = __builtin_amdgcn_mfma_f32_16x16x32_bf16(k0[sb * 2], qf[t][0], s, 0, 0, 0);
        s = __builtin_amdgcn_mfma_f32_16x16x32_bf16(k0[sb * 2 + 1], qf[t][1], s, 0, 0, 0);
        st[t][sb] = s;
      }
  }

  // strength-reduced reload pointers. Even step s=2su reloads K(2su+3),
  // V/M(2su+2); odd step reloads K(2su+4), V/M(2su+3) = mpF + 1024.
  // Advance: K/V += 4096, M += 2048 per su.
  const unsigned short* kpA = Kg + 3 * 2048;
  const unsigned short* kpB = Kg + 4 * 2048;
  const unsigned short* vpA = Vg + 2 * 2048;
  const unsigned short* vpB = Vg + 3 * 2048;
  const float* mpF = Mg + 2 * 1024;

  // half_step: exp(st_prev * m) -> pf ; QK(kf) -> st ; PV(vf, pf) -> acc.
  // kf holds K(step+1) at entry; vf/mf hold step's V/mask.
  auto half_step = [&](short8 (&kf)[4], short8 (&vf)[4], float4v (&mf)[4],
                       const unsigned short* kre, const unsigned short* vre,
                       const float* mre) {
    short8 pf[2];
#pragma unroll
    for (int t = 0; t < 2; ++t) {
      uint4v pw2;
#pragma unroll
      for (int sb = 0; sb < 2; ++sb) {
#pragma unroll
        for (int hh = 0; hh < 2; ++hh) {
          float p0 = __builtin_amdgcn_exp2f(st[t][sb][2 * hh] * mf[t * 2 + sb][hh * 2]);
          float p1 = __builtin_amdgcn_exp2f(st[t][sb][2 * hh + 1] * mf[t * 2 + sb][hh * 2 + 1]);
          pw2[sb * 2 + hh] = pk2bf(p0, p1);
        }
      }
      pf[t] = *(short8*)&pw2;
    }
    // mask reload (last use above)
#pragma unroll
    for (int i = 0; i < 4; ++i)
      mf[i] = *(const float4v*)(mre + i * 4);
    // QK for the NEXT step -> fresh st (independent of pf chain)
    __builtin_amdgcn_s_setprio(1);
#pragma unroll
    for (int t = 0; t < 2; ++t)
#pragma unroll
      for (int sb = 0; sb < 2; ++sb) {
        float4v s = {0, 0, 0, 0};
        s = __builtin_amdgcn_mfma_f32_16x16x32_bf16(kf[sb * 2], qf[t][0], s, 0, 0, 0);
        s = __builtin_amdgcn_mfma_f32_16x16x32_bf16(kf[sb * 2 + 1], qf[t][1], s, 0, 0, 0);
        st[t][sb] = s;
      }
    __builtin_amdgcn_s_setprio(0);
    // K reload (freed by QK above)
#pragma unroll
    for (int i = 0; i < 4; ++i)
      kf[i] = *(const short8*)(kre + i * 512);
    // PV + den
    __builtin_amdgcn_s_setprio(1);
#pragma unroll
    for (int nb = 0; nb < 4; ++nb) {
      acc[0][nb] = __builtin_amdgcn_mfma_f32_16x16x32_bf16(vf[nb], pf[0], acc[0][nb], 0, 0, 0);
      acc[1][nb] = __builtin_amdgcn_mfma_f32_16x16x32_bf16(vf[nb], pf[1], acc[1][nb], 0, 0, 0);
    }
    accd[0] = __builtin_amdgcn_mfma_f32_16x16x32_bf16(vones, pf[0], accd[0], 0, 0, 0);
    accd[1] = __builtin_amdgcn_mfma_f32_16x16x32_bf16(vones, pf[1], accd[1], 0, 0, 0);
    __builtin_amdgcn_s_setprio(0);
    // V reload (freed by PV above)
#pragma unroll
    for (int i = 0; i < 4; ++i)
      vf[i] = *(const short8*)(vre + i * 512);
  };

#pragma unroll 1
  for (int su = 0; su < 32; ++su) {
    half_step(kA, vA, mAf, kpA, vpA, mpF);
    half_step(kB, vB, mBf, kpB, vpB, mpF + 1024);
    kpA += 4096; kpB += 4096; vpA += 4096; vpB += 4096;
    mpF += 2048;
  }
  // final prefetches (steps 64..66) read past the bh's/mask's region into the
  // adjacent workspace buffer -- valid memory, values never consumed.

  // den[q=li] in lane li of accd[t][0] (row 0); epilogue O^T -> O, wave-private
  unsigned short* tr = tr_all + wv * (32 * 72);
#pragma unroll
  for (int t = 0; t < 2; ++t) {
    float den = __shfl(accd[t][0], li, 64);
    float rd = 1.0f / den;
#pragma unroll
    for (int nb = 0; nb < 4; ++nb) {
      int base = (t * 16 + li) * 72 + nb * 16 + g * 4;
      *(unsigned int*)(tr + base)     = pk2bf(acc[t][nb][0] * rd, acc[t][nb][1] * rd);
      *(unsigned int*)(tr + base + 2) = pk2bf(acc[t][nb][2] * rd, acc[t][nb][3] * rd);
    }
  }
  asm volatile("s_waitcnt lgkmcnt(0)" ::: "memory");

  int b = bh >> 4, h = bh & 15;
  int rrow = lane >> 3, part = lane & 7;
#pragma unroll
  for (int i = 0; i < 4; ++i) {
    int row = i * 8 + rrow;
    short8 o = *(const short8*)(tr + row * 72 + part * 8);
    *(short8*)(AO + ((size_t)(b * SS + q0 + row)) * EE + h * 64 + part * 8) = o;
  }
}

// ---------------------------------------------------------------------------
// Kernel 3: out = AO(4096x1024 bf16) @ WoT^T(bf16 [n][k]) + bo.
// R20 version: LDS-staged + XCD-locality mapping (XCD x owns n-tiles
// {2x,2x+1} -> per-XCD B working set 256KB, L2-hot). 128m x 64n tile, BK=64,
// grid 512 (2 blocks/CU). 4 waves, wave tile 64x32 (acc[4][2]).
// ---------------------------------------------------------------------------
__global__ __launch_bounds__(256) void out_gemm(
    const unsigned short* __restrict__ AO, const unsigned short* __restrict__ WoT,
    const float* __restrict__ bo, float* __restrict__ out)
{
  __shared__ __align__(16) unsigned short at[128 * 72];
  __shared__ __align__(16) unsigned short bt[64 * 72];
  int tid = threadIdx.x, wv = tid >> 6, lane = tid & 63;
  int li = lane & 15, g = lane >> 4;
  // XCD-locality mapping (bijective over 512 = 8 x 64):
  int xcd = blockIdx.x & 7, j = blockIdx.x >> 3;       // j = 0..63
  int n0 = (xcd * 2 + (j & 1)) * 64;                   // n-tile 0..15
  int m0 = (j >> 1) * 128;                             // m-tile 0..31
  int wm = (wv & 1) * 64, wn = (wv >> 1) * 32;

  const unsigned short* Ag = AO + (size_t)m0 * 1024;
  const unsigned short* Bg = WoT + (size_t)n0 * 1024;
  int srow = tid >> 3, scol = (tid & 7) * 8;

  short8 apre[4], bpre[2];
  auto ldst = [&](int k0) {
#pragma unroll
    for (int i = 0; i < 4; ++i)
      apre[i] = *(const short8*)(Ag + (size_t)(srow + i * 32) * 1024 + k0 + scol);
#pragma unroll
    for (int i = 0; i < 2; ++i) {
      int slot = tid + i * 256;
      int row = slot >> 3, col = (slot & 7) * 8;
      bpre[i] = *(const short8*)(Bg + (size_t)row * 1024 + k0 + col);
    }
  };

  float4v acc[4][2];
#pragma unroll
  for (int mt = 0; mt < 4; ++mt)
#pragma unroll
    for (int nt = 0; nt < 2; ++nt) acc[mt][nt] = (float4v){0, 0, 0, 0};

  ldst(0);
  for (int k0 = 0; k0 < 1024; k0 += 64) {
    __syncthreads();
#pragma unroll
    for (int i = 0; i < 4; ++i)
      *(short8*)(at + (srow + i * 32) * 72 + scol) = apre[i];
#pragma unroll
    for (int i = 0; i < 2; ++i) {
      int slot = tid + i * 256;
      int row = slot >> 3, col = (slot & 7) * 8;
      *(short8*)(bt + row * 72 + col) = bpre[i];
    }
    int nk = (k0 + 64 < 1024) ? k0 + 64 : 0;
    ldst(nk);
    __syncthreads();
#pragma unroll
    for (int ks = 0; ks < 2; ++ks) {
      short8 afr[4], bfr[2];
#pragma unroll
      for (int mt = 0; mt < 4; ++mt)
        afr[mt] = *(const short8*)(at + (wm + mt * 16 + li) * 72 + ks * 32 + g * 8);
#pragma unroll
      for (int nt = 0; nt < 2; ++nt)
        bfr[nt] = *(const short8*)(bt + (wn + nt * 16 + li) * 72 + ks * 32 + g * 8);
#pragma unroll
      for (int mt = 0; mt < 4; ++mt)
#pragma unroll
        for (int nt = 0; nt < 2; ++nt)
          acc[mt][nt] = __builtin_amdgcn_mfma_f32_16x16x32_bf16(afr[mt], bfr[nt], acc[mt][nt], 0, 0, 0);
    }
  }
#pragma unroll
  for (int nt = 0; nt < 2; ++nt) {
    float bof = bo[n0 + wn + nt * 16 + li];
#pragma unroll
    for (int mt = 0; mt < 4; ++mt)
#pragma unroll
      for (int r = 0; r < 4; ++r)
        out[(size_t)(m0 + wm + mt * 16 + g * 4 + r) * 1024 + n0 + wn + nt * 16 + li] =
            acc[mt][nt][r] + bof;
  }
}

// ---------------------------------------------------------------------------
extern "C" void kernel_launch(void* const* d_in, const int* in_sizes, int n_in,
                              void* d_out, int out_size, void* d_ws, size_t ws_size,
                              hipStream_t stream) {
  const float* x    = (const float*)d_in[0];
  const float* mask = (const float*)d_in[1];
  const float* Wq   = (const float*)d_in[2];
  const float* bq   = (const float*)d_in[3];
  const float* Wk   = (const float*)d_in[4];
  const float* bk   = (const float*)d_in[5];
  const float* Wv   = (const float*)d_in[6];
  const float* bv   = (const float*)d_in[7];
  const float* Wo   = (const float*)d_in[8];
  const float* bo   = (const float*)d_in[9];
  float* out = (float*)d_out;

  unsigned short* ws = (unsigned short*)d_ws;
  unsigned short* Q     = ws;                       // 8 MB
  unsigned short* Kp    = ws + 4194304;             // 8 MB
  unsigned short* Vf    = ws + 8388608;             // 8 MB
  unsigned short* AO    = ws + 12582912;            // 8 MB
  float*          maskPF = (float*)(ws + 16777216); // 16 MB (4M f32)
  unsigned short* WoT   = ws + 25165824;            // 2 MB  (total ~50 MB)

  fused_qkv<<<4864, 256, 0, stream>>>(x, Wq, Wk, Wv, bq, bk, bv, mask, Wo,
                                      Q, Kp, Vf, maskPF, WoT);
  attn_kernel<<<512, 256, 0, stream>>>(Q, Kp, Vf, maskPF, AO);
  out_gemm<<<512, 256, 0, stream>>>(AO, WoT, bo, out);
}

// Round 13
// 169.533 us; speedup vs baseline: 1.1159x; 1.1159x over previous
//
#include <hip/hip_runtime.h>
#include <hip/hip_bf16.h>

// B=2, S=2048, E=1024, H=16, HD=KD=VD=64. fp32 I/O, bf16 MFMA internals.
// R22 = R20 restored (best measured: 170.7us; attn 61.2us).
// R21's f32 mask cut VALU as predicted but doubled mask traffic+footprint
// (8->16MB, L2-thrash -> HBM-latency mask loads, +15us) -- reverted.
// attn: R18 structure (32 q-rows/wave, depth-2 ping-pong, st software
// pipeline, strength-reduced pointers, XCD swizzle, setprio, bf16 mask).
// out_gemm: LDS-staged + XCD-locality mapping. Single fused prep+qkv launch.
#define SS 2048
#define EE 1024
#define SCALE 0.125f
#define LOG2E 1.44269504088896f

typedef __attribute__((ext_vector_type(8))) short short8;
typedef __attribute__((ext_vector_type(4))) float float4v;
typedef __attribute__((ext_vector_type(4))) unsigned int uint4v;

__device__ __forceinline__ unsigned short f2bf(float f) {
  unsigned int u = __float_as_uint(f);
  unsigned int lsb = (u >> 16) & 1u;
  u += 0x7fffu + lsb;           // RNE
  return (unsigned short)(u >> 16);
}
__device__ __forceinline__ unsigned int pk2bf(float a, float b) {
  __hip_bfloat162 h = __float22bfloat162_rn(float2{a, b});
  return *reinterpret_cast<unsigned int*>(&h);
}

// ---------------------------------------------------------------------------
// Kernel 1 (fused): blocks 0..511 = QKV projection GEMM (local W3T);
// 512..2559 = mask pack -> maskP; 2560..2815 = Wo fp32 [k][n] -> WoT bf16
// [n][k]. qkv blocks dispatch first and start immediately; prep blocks
// backfill as qkv blocks retire.
//  Kp[bh][step][frag=sb*2+part][lane=g*16+(s&15)][j] = K[s][part*32+g*8+j]
//  Vf[bh][step][nb][lane=(pos>>3)*16+(d&15)][pos&7]  = V[s][d], pos=perm(s&31)
// ---------------------------------------------------------------------------
__global__ __launch_bounds__(256) void fused_qkv(
    const float* __restrict__ x,
    const float* __restrict__ Wq, const float* __restrict__ Wk,
    const float* __restrict__ Wv,
    const float* __restrict__ bq, const float* __restrict__ bk,
    const float* __restrict__ bv,
    const float* __restrict__ mask, const float* __restrict__ Wo,
    unsigned short* __restrict__ Q, unsigned short* __restrict__ Kp,
    unsigned short* __restrict__ Vf,
    unsigned short* __restrict__ maskP, unsigned short* __restrict__ WoT)
{
  __shared__ __align__(16) unsigned short w3t[192 * 72];
  __shared__ __align__(16) unsigned short xt[64 * 72];
  __shared__ __align__(16) unsigned short ob[12288];   // Q | Kp | Vf half-tile
  __shared__ float sBias[192];
  __shared__ unsigned short t[64 * 65];
  int blk = blockIdx.x;
  int tid = threadIdx.x;

  if (blk >= 512) {
    if (blk < 2560) {
      // ---- mask pack ----
      int idx = (blk - 512) * 256 + tid;
      int lane = idx & 63, step = (idx >> 6) & 63, qt = idx >> 12;
      int li = lane & 15, g = lane >> 4;
      const float c = SCALE * LOG2E;
      const float* mrow = mask + (size_t)(qt * 16 + li) * SS + step * 32 + g * 4;
      float4 a = *(const float4*)mrow;
      float4 bb = *(const float4*)(mrow + 16);
      uint4v o;
      o.x = pk2bf(a.x * c, a.y * c);
      o.y = pk2bf(a.z * c, a.w * c);
      o.z = pk2bf(bb.x * c, bb.y * c);
      o.w = pk2bf(bb.z * c, bb.w * c);
      *(uint4v*)(maskP + (size_t)idx * 8) = o;
      return;
    }
    // ---- Wo transpose: 64x64 tile per block ----
    int wblk = blk - 2560;                   // 0..255
    int k0 = (wblk >> 4) * 64, n0 = (wblk & 15) * 64;
#pragma unroll
    for (int i = 0; i < 16; ++i) {
      int e = tid + i * 256; int kk = e >> 6, nn = e & 63;
      t[nn * 65 + kk] = f2bf(Wo[(size_t)(k0 + kk) * 1024 + n0 + nn]);
    }
    __syncthreads();
#pragma unroll
    for (int i = 0; i < 16; ++i) {
      int e = tid + i * 256; int nn = e >> 6, kk = e & 63;
      WoT[(size_t)(n0 + nn) * 1024 + k0 + kk] = t[nn * 65 + kk];
    }
    return;
  }

  // ---- QKV projection ----
  int bh = blk >> 4;
  int s0blk = (blk & 15) * 128;
  int b = bh >> 4, h = bh & 15;
  int wv = tid >> 6, lane = tid & 63;
  int li = lane & 15, g = lane >> 4;

  // build w3t locally: w3t[(m*64+n)*72 + d] = bf16(W[d][n])  (W row-major)
  {
    const float* Ws[3] = {Wq, Wk, Wv};
#pragma unroll
    for (int m = 0; m < 3; ++m) {
      const float* W = Ws[m];
#pragma unroll
      for (int i = 0; i < 16; ++i) {
        int e = tid + i * 256; int d = e >> 6, n = e & 63;
        w3t[(m * 64 + n) * 72 + d] = f2bf(W[e]);
      }
    }
  }
  if (tid < 192) sBias[tid] = (tid < 64) ? bq[tid] : (tid < 128 ? bk[tid - 64] : bv[tid - 128]);

  for (int half = 0; half < 2; ++half) {
    int s0 = s0blk + half * 64;
    if (half) __syncthreads();        // prior half's ob/xt reads done
    const float* xbase = x + ((size_t)(b * SS + s0)) * EE + h * 64;
#pragma unroll
    for (int it = 0; it < 4; ++it) {
      int flat = tid + it * 256;
      int row = flat >> 4, ch = flat & 15;
      float4 v = *(const float4*)(xbase + (size_t)row * EE + ch * 4);
      uint2 u; u.x = pk2bf(v.x, v.y); u.y = pk2bf(v.z, v.w);
      *(uint2*)(xt + row * 72 + ch * 4) = u;
    }
    __syncthreads();   // covers w3t/sBias (half 0) and xt

    int mrow = wv * 16;
    short8 af[2];
#pragma unroll
    for (int ks = 0; ks < 2; ++ks)
      af[ks] = *(const short8*)(xt + (mrow + li) * 72 + ks * 32 + g * 8);

    float4v acc[12];
#pragma unroll
    for (int i = 0; i < 12; ++i) acc[i] = (float4v){0, 0, 0, 0};
#pragma unroll
    for (int ks = 0; ks < 2; ++ks)
#pragma unroll
      for (int nb = 0; nb < 12; ++nb) {
        short8 bfr = *(const short8*)(w3t + (nb * 16 + li) * 72 + ks * 32 + g * 8);
        acc[nb] = __builtin_amdgcn_mfma_f32_16x16x32_bf16(af[ks], bfr, acc[nb], 0, 0, 0);
      }

    // scatter into LDS reorder buffer
#pragma unroll
    for (int nb = 0; nb < 12; ++nb) {
      float bias = sBias[nb * 16 + li];
      int mtx = nb >> 2, sub = nb & 3;
#pragma unroll
      for (int r = 0; r < 4; ++r) {
        unsigned short v = f2bf(acc[nb][r] + bias);
        int sl = mrow + g * 4 + r;         // 0..63 local row
        int stp = sl >> 5, s5 = sl & 31;
        if (mtx == 0) {
          ob[sl * 64 + sub * 16 + li] = v;
        } else if (mtx == 1) {
          int sb = s5 >> 4, lik = s5 & 15;
          int part = sub >> 1;
          int gk = ((sub & 1) << 1) | (li >> 3);
          ob[4096 + stp * 2048 + (sb * 2 + part) * 512 + (gk * 16 + lik) * 8 + (li & 7)] = v;
        } else {
          int pos = ((s5 >> 2) & 3) * 8 + ((s5 >> 4) & 1) * 4 + (s5 & 3);
          ob[8192 + stp * 2048 + sub * 512 + ((pos >> 3) * 16 + li) * 8 + (pos & 7)] = v;
        }
      }
    }
    __syncthreads();

    // coalesced b128 stores: 1536 slots of 8 elems
    unsigned short* Qg = Q + ((size_t)bh * SS + s0) * 64;
    unsigned short* Kg = Kp + (size_t)bh * 131072 + (s0 >> 5) * 2048;
    unsigned short* Vg = Vf + (size_t)bh * 131072 + (s0 >> 5) * 2048;
#pragma unroll
    for (int i = 0; i < 6; ++i) {
      int slot = tid + i * 256;          // 0..1535
      int rgn = slot >> 9, off = (slot & 511) * 8;
      short8 v = *(const short8*)(ob + rgn * 4096 + off);
      unsigned short* dst = (rgn == 0) ? (Qg + off) : (rgn == 1 ? (Kg + off) : (Vg + off));
      *(short8*)dst = v;
    }
  }
}

// ---------------------------------------------------------------------------
// Kernel 2: flash attention (R13 structure + R18 edits). Wave = 32 q-rows of
// one bh; block = 4 independent waves; grid 512 (bijective XCD swizzle).
// All K/V/mask fragments loaded global->registers. S^T formulation; den via
// ones-row MFMA. 1-step software pipeline of st; depth-2 K/V/mask ping-pong;
// strength-reduced reload pointers; setprio around MFMA clusters.
// ---------------------------------------------------------------------------
__global__ __launch_bounds__(256) void attn_kernel(
    const unsigned short* __restrict__ Q, const unsigned short* __restrict__ Kp,
    const unsigned short* __restrict__ Vf, const unsigned short* __restrict__ maskP,
    unsigned short* __restrict__ AO)
{
  __shared__ __align__(16) unsigned short tr_all[4 * 32 * 72];  // epilogue only
  int tid = threadIdx.x, wv = tid >> 6, lane = tid & 63;
  int li = lane & 15, g = lane >> 4;
  // bijective XCD swizzle: 512 = 8 XCDs x 64 -> XCD x hosts bh [4x, 4x+4)
  int virt = (blockIdx.x & 7) * 64 + (blockIdx.x >> 3);
  int wave_id = virt * 4 + wv;              // 0..2047
  int bh = wave_id >> 6;
  int q0 = (wave_id & 63) * 32;

  short8 qf[2][2];
#pragma unroll
  for (int t = 0; t < 2; ++t) {
    const unsigned short* Qb = Q + ((size_t)bh * SS + q0 + t * 16 + li) * 64;
    qf[t][0] = *(const short8*)(Qb + g * 8);
    qf[t][1] = *(const short8*)(Qb + 32 + g * 8);
  }

  const unsigned short* Kg = Kp + (size_t)bh * 131072 + lane * 8;
  const unsigned short* Vg = Vf + (size_t)bh * 131072 + lane * 8;
  const unsigned short* Mg0 = maskP + (size_t)(q0 >> 4) * 32768 + lane * 8;
  const unsigned short* Mg1 = Mg0 + 32768;

  unsigned short ov = (li == 0) ? (unsigned short)0x3F80 : (unsigned short)0;
  short8 vones = {(short)ov, (short)ov, (short)ov, (short)ov,
                  (short)ov, (short)ov, (short)ov, (short)ov};

  float4v acc[2][4];
#pragma unroll
  for (int t = 0; t < 2; ++t)
#pragma unroll
    for (int nb = 0; nb < 4; ++nb) acc[t][nb] = (float4v){0, 0, 0, 0};
  float4v accd[2] = {{0, 0, 0, 0}, {0, 0, 0, 0}};

  // carried score registers (software-pipeline stage): st[t][sb] holds the
  // QK output for the step whose exp has NOT run yet.
  float4v st[2][2];

  // ping-pong prefetch sets: A = even steps, B = odd steps (depth-2)
  short8 kA[4], kB[4], vA[4], vB[4];
  uint4v mA0, mA1, mB0, mB1;
  {
    short8 k0[4];
#pragma unroll
    for (int i = 0; i < 4; ++i) {
      k0[i] = *(const short8*)(Kg + i * 512);
      kA[i] = *(const short8*)(Kg + 2048 + i * 512);
      kB[i] = *(const short8*)(Kg + 2 * 2048 + i * 512);
      vA[i] = *(const short8*)(Vg + i * 512);
      vB[i] = *(const short8*)(Vg + 2048 + i * 512);
    }
    mA0 = *(const uint4v*)Mg0;
    mA1 = *(const uint4v*)Mg1;
    mB0 = *(const uint4v*)(Mg0 + 512);
    mB1 = *(const uint4v*)(Mg1 + 512);
    // prologue QK: st <- scores(step 0)
#pragma unroll
    for (int t = 0; t < 2; ++t)
#pragma unroll
      for (int sb = 0; sb < 2; ++sb) {
        float4v s = {0, 0, 0, 0};
        s = __builtin_amdgcn_mfma_f32_16x16x32_bf16(k0[sb * 2], qf[t][0], s, 0, 0, 0);
        s = __builtin_amdgcn_mfma_f32_16x16x32_bf16(k0[sb * 2 + 1], qf[t][1], s, 0, 0, 0);
        st[t][sb] = s;
      }
  }

  // strength-reduced reload pointers. Even step s=2su reloads K(2su+3),
  // V/M(2su+2); odd step s=2su+1 reloads K(2su+4), V/M(2su+3). Mask odd =
  // mp + 512 (1KB immediate offset). Advance: K/V += 4096, M += 1024 per su.
  const unsigned short* kpA = Kg + 3 * 2048;
  const unsigned short* kpB = Kg + 4 * 2048;
  const unsigned short* vpA = Vg + 2 * 2048;
  const unsigned short* vpB = Vg + 3 * 2048;
  const unsigned short* mp0 = Mg0 + 2 * 512;
  const unsigned short* mp1 = Mg1 + 2 * 512;

  // half_step: exp(st_prev, m) -> pf ; QK(kf) -> st ; PV(vf, pf) -> acc.
  // kf holds K(step+1) at entry; vf/m hold step's V/mask.
  auto half_step = [&](short8 (&kf)[4], short8 (&vf)[4], uint4v& m0c, uint4v& m1c,
                       const unsigned short* kre, const unsigned short* vre,
                       const unsigned short* mre0, const unsigned short* mre1) {
    short8 pf[2];
#pragma unroll
    for (int t = 0; t < 2; ++t) {
      uint4v pw2;
#pragma unroll
      for (int sb = 0; sb < 2; ++sb) {
#pragma unroll
        for (int hh = 0; hh < 2; ++hh) {
          unsigned int mm = (t == 0) ? m0c[sb * 2 + hh] : m1c[sb * 2 + hh];
          float p0 = __builtin_amdgcn_exp2f(st[t][sb][2 * hh] * __uint_as_float(mm << 16));
          float p1 = __builtin_amdgcn_exp2f(st[t][sb][2 * hh + 1] * __uint_as_float(mm & 0xffff0000u));
          pw2[sb * 2 + hh] = pk2bf(p0, p1);
        }
      }
      pf[t] = *(short8*)&pw2;
    }
    // mask reload (last use above)
    m0c = *(const uint4v*)mre0;
    m1c = *(const uint4v*)mre1;
    // QK for the NEXT step -> fresh st (independent of pf chain)
    __builtin_amdgcn_s_setprio(1);
#pragma unroll
    for (int t = 0; t < 2; ++t)
#pragma unroll
      for (int sb = 0; sb < 2; ++sb) {
        float4v s = {0, 0, 0, 0};
        s = __builtin_amdgcn_mfma_f32_16x16x32_bf16(kf[sb * 2], qf[t][0], s, 0, 0, 0);
        s = __builtin_amdgcn_mfma_f32_16x16x32_bf16(kf[sb * 2 + 1], qf[t][1], s, 0, 0, 0);
        st[t][sb] = s;
      }
    __builtin_amdgcn_s_setprio(0);
    // K reload (freed by QK above)
#pragma unroll
    for (int i = 0; i < 4; ++i)
      kf[i] = *(const short8*)(kre + i * 512);
    // PV + den
    __builtin_amdgcn_s_setprio(1);
#pragma unroll
    for (int nb = 0; nb < 4; ++nb) {
      acc[0][nb] = __builtin_amdgcn_mfma_f32_16x16x32_bf16(vf[nb], pf[0], acc[0][nb], 0, 0, 0);
      acc[1][nb] = __builtin_amdgcn_mfma_f32_16x16x32_bf16(vf[nb], pf[1], acc[1][nb], 0, 0, 0);
    }
    accd[0] = __builtin_amdgcn_mfma_f32_16x16x32_bf16(vones, pf[0], accd[0], 0, 0, 0);
    accd[1] = __builtin_amdgcn_mfma_f32_16x16x32_bf16(vones, pf[1], accd[1], 0, 0, 0);
    __builtin_amdgcn_s_setprio(0);
    // V reload (freed by PV above)
#pragma unroll
    for (int i = 0; i < 4; ++i)
      vf[i] = *(const short8*)(vre + i * 512);
  };

#pragma unroll 1
  for (int su = 0; su < 32; ++su) {
    half_step(kA, vA, mA0, mA1, kpA, vpA, mp0, mp1);
    half_step(kB, vB, mB0, mB1, kpB, vpB, mp0 + 512, mp1 + 512);
    kpA += 4096; kpB += 4096; vpA += 4096; vpB += 4096;
    mp0 += 1024; mp1 += 1024;
  }
  // final prefetches (steps 64..66) read past the bh's region into the next
  // workspace buffer -- valid memory, values never consumed.

  // den[q=li] in lane li of accd[t][0] (row 0); epilogue O^T -> O, wave-private
  unsigned short* tr = tr_all + wv * (32 * 72);
#pragma unroll
  for (int t = 0; t < 2; ++t) {
    float den = __shfl(accd[t][0], li, 64);
    float rd = 1.0f / den;
#pragma unroll
    for (int nb = 0; nb < 4; ++nb) {
      int base = (t * 16 + li) * 72 + nb * 16 + g * 4;
      *(unsigned int*)(tr + base)     = pk2bf(acc[t][nb][0] * rd, acc[t][nb][1] * rd);
      *(unsigned int*)(tr + base + 2) = pk2bf(acc[t][nb][2] * rd, acc[t][nb][3] * rd);
    }
  }
  asm volatile("s_waitcnt lgkmcnt(0)" ::: "memory");

  int b = bh >> 4, h = bh & 15;
  int rrow = lane >> 3, part = lane & 7;
#pragma unroll
  for (int i = 0; i < 4; ++i) {
    int row = i * 8 + rrow;
    short8 o = *(const short8*)(tr + row * 72 + part * 8);
    *(short8*)(AO + ((size_t)(b * SS + q0 + row)) * EE + h * 64 + part * 8) = o;
  }
}

// ---------------------------------------------------------------------------
// Kernel 3: out = AO(4096x1024 bf16) @ WoT^T(bf16 [n][k]) + bo.
// LDS-staged + XCD-locality mapping: XCD x (=blk&7) owns n-tiles {2x,2x+1}
// -> per-XCD B working set 256KB (L2-hot); m-tile = j>>1. 128m x 64n tile,
// BK=64, grid 512 (2 blocks/CU). 4 waves, wave tile 64x32 (acc[4][2]).
// ---------------------------------------------------------------------------
__global__ __launch_bounds__(256) void out_gemm(
    const unsigned short* __restrict__ AO, const unsigned short* __restrict__ WoT,
    const float* __restrict__ bo, float* __restrict__ out)
{
  __shared__ __align__(16) unsigned short at[128 * 72];
  __shared__ __align__(16) unsigned short bt[64 * 72];
  int tid = threadIdx.x, wv = tid >> 6, lane = tid & 63;
  int li = lane & 15, g = lane >> 4;
  // XCD-locality mapping (bijective over 512 = 8 x 64):
  int xcd = blockIdx.x & 7, j = blockIdx.x >> 3;       // j = 0..63
  int n0 = (xcd * 2 + (j & 1)) * 64;                   // n-tile 0..15
  int m0 = (j >> 1) * 128;                             // m-tile 0..31
  int wm = (wv & 1) * 64, wn = (wv >> 1) * 32;

  const unsigned short* Ag = AO + (size_t)m0 * 1024;
  const unsigned short* Bg = WoT + (size_t)n0 * 1024;
  int srow = tid >> 3, scol = (tid & 7) * 8;

  short8 apre[4], bpre[2];
  auto ldst = [&](int k0) {
#pragma unroll
    for (int i = 0; i < 4; ++i)
      apre[i] = *(const short8*)(Ag + (size_t)(srow + i * 32) * 1024 + k0 + scol);
#pragma unroll
    for (int i = 0; i < 2; ++i) {
      int slot = tid + i * 256;
      int row = slot >> 3, col = (slot & 7) * 8;
      bpre[i] = *(const short8*)(Bg + (size_t)row * 1024 + k0 + col);
    }
  };

  float4v acc[4][2];
#pragma unroll
  for (int mt = 0; mt < 4; ++mt)
#pragma unroll
    for (int nt = 0; nt < 2; ++nt) acc[mt][nt] = (float4v){0, 0, 0, 0};

  ldst(0);
  for (int k0 = 0; k0 < 1024; k0 += 64) {
    __syncthreads();
#pragma unroll
    for (int i = 0; i < 4; ++i)
      *(short8*)(at + (srow + i * 32) * 72 + scol) = apre[i];
#pragma unroll
    for (int i = 0; i < 2; ++i) {
      int slot = tid + i * 256;
      int row = slot >> 3, col = (slot & 7) * 8;
      *(short8*)(bt + row * 72 + col) = bpre[i];
    }
    int nk = (k0 + 64 < 1024) ? k0 + 64 : 0;
    ldst(nk);
    __syncthreads();
#pragma unroll
    for (int ks = 0; ks < 2; ++ks) {
      short8 afr[4], bfr[2];
#pragma unroll
      for (int mt = 0; mt < 4; ++mt)
        afr[mt] = *(const short8*)(at + (wm + mt * 16 + li) * 72 + ks * 32 + g * 8);
#pragma unroll
      for (int nt = 0; nt < 2; ++nt)
        bfr[nt] = *(const short8*)(bt + (wn + nt * 16 + li) * 72 + ks * 32 + g * 8);
#pragma unroll
      for (int mt = 0; mt < 4; ++mt)
#pragma unroll
        for (int nt = 0; nt < 2; ++nt)
          acc[mt][nt] = __builtin_amdgcn_mfma_f32_16x16x32_bf16(afr[mt], bfr[nt], acc[mt][nt], 0, 0, 0);
    }
  }
#pragma unroll
  for (int nt = 0; nt < 2; ++nt) {
    float bof = bo[n0 + wn + nt * 16 + li];
#pragma unroll
    for (int mt = 0; mt < 4; ++mt)
#pragma unroll
      for (int r = 0; r < 4; ++r)
        out[(size_t)(m0 + wm + mt * 16 + g * 4 + r) * 1024 + n0 + wn + nt * 16 + li] =
            acc[mt][nt][r] + bof;
  }
}

// ---------------------------------------------------------------------------
extern "C" void kernel_launch(void* const* d_in, const int* in_sizes, int n_in,
                              void* d_out, int out_size, void* d_ws, size_t ws_size,
                              hipStream_t stream) {
  const float* x    = (const float*)d_in[0];
  const float* mask = (const float*)d_in[1];
  const float* Wq   = (const float*)d_in[2];
  const float* bq   = (const float*)d_in[3];
  const float* Wk   = (const float*)d_in[4];
  const float* bk   = (const float*)d_in[5];
  const float* Wv   = (const float*)d_in[6];
  const float* bv   = (const float*)d_in[7];
  const float* Wo   = (const float*)d_in[8];
  const float* bo   = (const float*)d_in[9];
  float* out = (float*)d_out;

  unsigned short* ws = (unsigned short*)d_ws;
  unsigned short* Q     = ws;
  unsigned short* Kp    = ws + 4194304;
  unsigned short* Vf    = ws + 8388608;
  unsigned short* AO    = ws + 12582912;
  unsigned short* maskP = ws + 16777216;
  unsigned short* WoT   = ws + 20971520;   // 1M shorts (2MB)

  fused_qkv<<<2816, 256, 0, stream>>>(x, Wq, Wk, Wv, bq, bk, bv, mask, Wo,
                                      Q, Kp, Vf, maskP, WoT);
  attn_kernel<<<512, 256, 0, stream>>>(Q, Kp, Vf, maskP, AO);
  out_gemm<<<512, 256, 0, stream>>>(AO, WoT, bo, out);
}